// Round 3
// baseline (444.485 us; speedup 1.0000x reference)
//
#include <hip/hip_runtime.h>
#include <stdint.h>

#define T_ 256
#define B_ 8
#define E_ 512
#define H_ 32
#define HD_ 16
#define EXP_ 512
#define S_ 768          // T_ + EXP_
#define M_ 2048         // T_ * B_
#define SMOOTH_ 20.0f

// ---------------------------------------------------------------------------
// GEMM core (unchanged from round 1): C[m][n] = sum_e X[m][e] * W[n][e].
// ---------------------------------------------------------------------------
__device__ __forceinline__ void gemm_body(const float* __restrict__ X,
                                          const float* __restrict__ W,
                                          int m0, int n0,
                                          float acc[4][4],
                                          float* Xs, float* Ws)
{
    const int tid = threadIdx.x;
    const int lr  = tid >> 2;
    const int lc4 = tid & 3;
    const int tx  = tid & 15;
    const int ty  = tid >> 4;

    for (int k0 = 0; k0 < E_; k0 += 16) {
        float4 xv = *(const float4*)&X[(size_t)(m0 + lr) * E_ + k0 + lc4 * 4];
        float4 wv = *(const float4*)&W[(size_t)(n0 + lr) * E_ + k0 + lc4 * 4];
        __syncthreads();
        Xs[(lc4 * 4 + 0) * 64 + lr] = xv.x;
        Xs[(lc4 * 4 + 1) * 64 + lr] = xv.y;
        Xs[(lc4 * 4 + 2) * 64 + lr] = xv.z;
        Xs[(lc4 * 4 + 3) * 64 + lr] = xv.w;
        Ws[(lc4 * 4 + 0) * 64 + lr] = wv.x;
        Ws[(lc4 * 4 + 1) * 64 + lr] = wv.y;
        Ws[(lc4 * 4 + 2) * 64 + lr] = wv.z;
        Ws[(lc4 * 4 + 3) * 64 + lr] = wv.w;
        __syncthreads();
#pragma unroll
        for (int kk = 0; kk < 16; ++kk) {
            float4 a4 = *(const float4*)&Xs[kk * 64 + ty * 4];
            float4 b4 = *(const float4*)&Ws[kk * 64 + tx * 4];
            float a[4] = {a4.x, a4.y, a4.z, a4.w};
            float b[4] = {b4.x, b4.y, b4.z, b4.w};
#pragma unroll
            for (int i = 0; i < 4; ++i)
#pragma unroll
                for (int j = 0; j < 4; ++j)
                    acc[i][j] += a[i] * b[j];
        }
    }
}

__global__ __launch_bounds__(256)
void qkv_gemm(const float* __restrict__ X,
              const float* __restrict__ Wq, const float* __restrict__ bq,
              const float* __restrict__ Wk,
              const float* __restrict__ Wv, const float* __restrict__ bv,
              float* __restrict__ Q, float* __restrict__ K, float* __restrict__ V)
{
    __shared__ float Xs[16 * 64];
    __shared__ float Ws[16 * 64];
    const int z = blockIdx.z;
    const float* W    = (z == 0) ? Wq : (z == 1 ? Wk : Wv);
    const float* bias = (z == 0) ? bq : (z == 1 ? nullptr : bv);
    float* dst        = (z == 0) ? Q  : (z == 1 ? K  : V);
    const int rows    = (z == 0) ? T_ : S_;

    const int m0 = blockIdx.y * 64;
    const int n0 = blockIdx.x * 64;
    float acc[4][4] = {};
    gemm_body(X, W, m0, n0, acc, Xs, Ws);

    const int tx = threadIdx.x & 15;
    const int ty = threadIdx.x >> 4;
    float4 bias4 = make_float4(0.f, 0.f, 0.f, 0.f);
    if (bias) bias4 = *(const float4*)&bias[n0 + tx * 4];
#pragma unroll
    for (int i = 0; i < 4; ++i) {
        const int m = m0 + ty * 4 + i;
        const int t = m >> 3;
        const int b = m & 7;
        const int n = n0 + tx * 4;
        const int h = n >> 4;
        const int d = n & 15;
        float4 o;
        o.x = acc[i][0] + bias4.x;
        o.y = acc[i][1] + bias4.y;
        o.z = acc[i][2] + bias4.z;
        o.w = acc[i][3] + bias4.w;
        *(float4*)&dst[(((size_t)(b * H_ + h)) * rows + t) * HD_ + d] = o;
    }
}

__global__ __launch_bounds__(256)
void out_gemm(const float* __restrict__ X, const float* __restrict__ Wo,
              const float* __restrict__ bo, float* __restrict__ dst)
{
    __shared__ float Xs[16 * 64];
    __shared__ float Ws[16 * 64];
    const int m0 = blockIdx.y * 64;
    const int n0 = blockIdx.x * 64;
    float acc[4][4] = {};
    gemm_body(X, Wo, m0, n0, acc, Xs, Ws);

    const int tx = threadIdx.x & 15;
    const int ty = threadIdx.x >> 4;
    float4 bias4 = *(const float4*)&bo[n0 + tx * 4];
#pragma unroll
    for (int i = 0; i < 4; ++i) {
        const int m = m0 + ty * 4 + i;
        float4 o;
        o.x = acc[i][0] + bias4.x;
        o.y = acc[i][1] + bias4.y;
        o.z = acc[i][2] + bias4.z;
        o.w = acc[i][3] + bias4.w;
        *(float4*)&dst[(size_t)m * E_ + n0 + tx * 4] = o;
    }
}

// ---------------------------------------------------------------------------
// K/V expansion gather (unchanged).
// ---------------------------------------------------------------------------
__global__ __launch_bounds__(256)
void gather_kernel(const int* __restrict__ oc,
                   float* __restrict__ Kb, float* __restrict__ Vb)
{
    const int bj  = blockIdx.x;
    const int b   = bj >> 9;
    const int j   = bj & 511;
    const int src = oc[bj];

    const int tid   = threadIdx.x;
    const int which = tid >> 7;
    const int i     = tid & 127;
    const int h     = i >> 2;
    const int f4    = i & 3;
    float* P = which ? Vb : Kb;
    const float4* s4 = (const float4*)&P[(((size_t)(b * H_ + h)) * S_ + src) * HD_];
    float4*       d4 = (float4*)&P[(((size_t)(b * H_ + h)) * S_ + T_ + j) * HD_];
    d4[f4] = s4[f4];
}

// ---------------------------------------------------------------------------
// Attention v2: 1024 threads (16 waves) per (b,h) block.
// Thread = 2 t-rows x 1/8 of the s-range. Layout:
//   w = tid>>6 (wave), l = tid&63; tl = l&15; lg = l>>4
//   t0 = (w&7)*32 + tl*2  (rows t0, t0+1)
//   sg = (w>>3)*4 + lg    (8 s-subsets; rows taken mod 8 so concurrent
//                          lane-group LDS reads hit mixed bank parities)
// Each K/V LDS row read serves 2 t-rows (DS inst count halved).
// End: shuffle-reduce over lane-groups (xor 16,32), then the two wave-halves
// combine through a 17 KB LDS buffer aliased onto the staging region.
// Fixed-reference softmax: x in ~[-30,30], exp(x-50) never over/underflows.
// ---------------------------------------------------------------------------
__global__ __launch_bounds__(1024)
void attn_kernel(const float* __restrict__ Q, const float* __restrict__ Kb,
                 const float* __restrict__ Vb, const float* __restrict__ LAW,
                 const int* __restrict__ kpm, const int* __restrict__ em,
                 float* __restrict__ A)
{
    __shared__ float lds[8448];          // Ks[4096] | Vs[4096] | ms[256]
    float* Ks  = lds;
    float* Vs  = lds + 4096;
    int*   ms  = (int*)(lds + 8192);
    float* redA = lds;                   // alias, used after compute
    float* redZ = lds + 4096;            // alias

    const int bh  = blockIdx.x;
    const int b   = bh >> 5;
    const int h   = bh & 31;
    const int tid = threadIdx.x;
    const int w   = tid >> 6;
    const int l   = tid & 63;
    const int tl  = l & 15;
    const int lg  = l >> 4;
    const int t0  = (w & 7) * 32 + tl * 2;
    const int sg  = ((w >> 3) << 2) + lg;   // 0..7

    float q0[16], q1[16];
    {
        const float4* qp = (const float4*)&Q[((size_t)bh * T_ + t0) * HD_];
#pragma unroll
        for (int i = 0; i < 4; ++i) {
            float4 v = qp[i];
            q0[4 * i + 0] = v.x; q0[4 * i + 1] = v.y;
            q0[4 * i + 2] = v.z; q0[4 * i + 3] = v.w;
            float4 u = qp[i + 4];
            q1[4 * i + 0] = u.x; q1[4 * i + 1] = u.y;
            q1[4 * i + 2] = u.z; q1[4 * i + 3] = u.w;
        }
    }

    float acc0[16] = {}, acc1[16] = {};
    float Z0 = 0.f, Z1 = 0.f;
    const float* law0 = &LAW[((size_t)b * T_ + t0) * S_];
    const float* law1 = law0 + S_;

    for (int s0 = 0; s0 < S_; s0 += 256) {
        __syncthreads();
        ((float4*)Ks)[tid] = ((const float4*)&Kb[((size_t)bh * S_ + s0) * HD_])[tid];
        ((float4*)Vs)[tid] = ((const float4*)&Vb[((size_t)bh * S_ + s0) * HD_])[tid];
        if (tid < 256) {
            const int s = s0 + tid;
            ms[tid] = (s < T_) ? kpm[b * T_ + s] : em[b * EXP_ + (s - T_)];
        }
        __syncthreads();

#pragma unroll 2
        for (int j = 0; j < 32; ++j) {
            const int r = j * 8 + sg;          // local row in [0,256)
            const int s = s0 + r;
            const float4* kr = (const float4*)&Ks[r * 16];
            float4 ka = kr[0], kb4 = kr[1], kc = kr[2], kd = kr[3];
            const float lw0 = law0[s];
            const float lw1 = law1[s];
            const int   msk = ms[r];

            // row 0 score, 4 partial sums
            float p0 = q0[0] * ka.x  + q0[1] * ka.y  + q0[2] * ka.z  + q0[3] * ka.w;
            float p1 = q0[4] * kb4.x + q0[5] * kb4.y + q0[6] * kb4.z + q0[7] * kb4.w;
            float p2 = q0[8] * kc.x  + q0[9] * kc.y  + q0[10] * kc.z + q0[11] * kc.w;
            float p3 = q0[12] * kd.x + q0[13] * kd.y + q0[14] * kd.z + q0[15] * kd.w;
            const float sc0 = (p0 + p1) + (p2 + p3);
            // row 1 score
            float r0 = q1[0] * ka.x  + q1[1] * ka.y  + q1[2] * ka.z  + q1[3] * ka.w;
            float r1 = q1[4] * kb4.x + q1[5] * kb4.y + q1[6] * kb4.z + q1[7] * kb4.w;
            float r2 = q1[8] * kc.x  + q1[9] * kc.y  + q1[10] * kc.z + q1[11] * kc.w;
            float r3 = q1[12] * kd.x + q1[13] * kd.y + q1[14] * kd.z + q1[15] * kd.w;
            const float sc1 = (r0 + r1) + (r2 + r3);

            const float x0 = (sc0 + SMOOTH_) * lw0 - SMOOTH_;
            const float x1 = (sc1 + SMOOTH_) * lw1 - SMOOTH_;
            const float e0 = msk ? 0.f : __expf(x0 - 50.f);
            const float e1 = msk ? 0.f : __expf(x1 - 50.f);
            Z0 += e0; Z1 += e1;
            const float w0 = e0 * lw0;
            const float w1 = e1 * lw1;

            const float4* vr = (const float4*)&Vs[r * 16];
#pragma unroll
            for (int i = 0; i < 4; ++i) {
                float4 vv = vr[i];
                acc0[4 * i + 0] += w0 * vv.x; acc1[4 * i + 0] += w1 * vv.x;
                acc0[4 * i + 1] += w0 * vv.y; acc1[4 * i + 1] += w1 * vv.y;
                acc0[4 * i + 2] += w0 * vv.z; acc1[4 * i + 2] += w1 * vv.z;
                acc0[4 * i + 3] += w0 * vv.w; acc1[4 * i + 3] += w1 * vv.w;
            }
        }
    }

    __syncthreads();   // all compute done; staging LDS may now be aliased

    // reduce across lane-groups (lanes l, l^16, l^32, l^48 — same wave)
#pragma unroll
    for (int i = 0; i < 16; ++i) {
        acc0[i] += __shfl_xor(acc0[i], 16);
        acc0[i] += __shfl_xor(acc0[i], 32);
        acc1[i] += __shfl_xor(acc1[i], 16);
        acc1[i] += __shfl_xor(acc1[i], 32);
    }
    Z0 += __shfl_xor(Z0, 16); Z0 += __shfl_xor(Z0, 32);
    Z1 += __shfl_xor(Z1, 16); Z1 += __shfl_xor(Z1, 32);

    if (lg == 0 && w >= 8) {
        float4* ra0 = (float4*)&redA[t0 * 16];
#pragma unroll
        for (int i = 0; i < 4; ++i) {
            ra0[i]     = make_float4(acc0[4 * i], acc0[4 * i + 1], acc0[4 * i + 2], acc0[4 * i + 3]);
            ra0[i + 4] = make_float4(acc1[4 * i], acc1[4 * i + 1], acc1[4 * i + 2], acc1[4 * i + 3]);
        }
        redZ[t0]     = Z0;
        redZ[t0 + 1] = Z1;
    }
    __syncthreads();
    if (lg == 0 && w < 8) {
#pragma unroll
        for (int i = 0; i < 16; ++i) {
            acc0[i] += redA[t0 * 16 + i];
            acc1[i] += redA[(t0 + 1) * 16 + i];
        }
        Z0 += redZ[t0];
        Z1 += redZ[t0 + 1];
        const float inv0 = (Z0 > 0.f) ? 1.f / Z0 : 0.f;
        const float inv1 = (Z1 > 0.f) ? 1.f / Z1 : 0.f;
        float4* op0 = (float4*)&A[(((size_t)t0 * B_) + b) * E_ + h * HD_];
        float4* op1 = (float4*)&A[(((size_t)(t0 + 1) * B_) + b) * E_ + h * HD_];
#pragma unroll
        for (int i = 0; i < 4; ++i) {
            op0[i] = make_float4(acc0[4 * i] * inv0, acc0[4 * i + 1] * inv0,
                                 acc0[4 * i + 2] * inv0, acc0[4 * i + 3] * inv0);
            op1[i] = make_float4(acc1[4 * i] * inv1, acc1[4 * i + 1] * inv1,
                                 acc1[4 * i + 2] * inv1, acc1[4 * i + 3] * inv1);
        }
    }
}

// ---------------------------------------------------------------------------
extern "C" void kernel_launch(void* const* d_in, const int* in_sizes, int n_in,
                              void* d_out, int out_size, void* d_ws, size_t ws_size,
                              hipStream_t stream)
{
    const float* query = (const float*)d_in[0];
    const int*   oc    = (const int*)d_in[1];
    const int*   em    = (const int*)d_in[2];
    const int*   kpm   = (const int*)d_in[3];
    const float* law   = (const float*)d_in[4];
    const float* Wq    = (const float*)d_in[5];
    const float* bq    = (const float*)d_in[6];
    const float* Wk    = (const float*)d_in[7];
    const float* Wv    = (const float*)d_in[8];
    const float* bv    = (const float*)d_in[9];
    const float* Wo    = (const float*)d_in[10];
    const float* bo    = (const float*)d_in[11];
    float* out = (float*)d_out;

    float* ws = (float*)d_ws;
    float* Q = ws;                       // [B][H][T][16]
    float* K = Q + (size_t)1048576;      // [B][H][S][16]
    float* V = K + (size_t)3145728;      // [B][H][S][16]
    float* A = V + (size_t)3145728;      // [t][b][e]

    dim3 gq(E_ / 64, M_ / 64, 3);
    qkv_gemm<<<gq, 256, 0, stream>>>(query, Wq, bq, Wk, Wv, bv, Q, K, V);

    gather_kernel<<<B_ * EXP_, 256, 0, stream>>>(oc, K, V);

    attn_kernel<<<B_ * H_, 1024, 0, stream>>>(Q, K, V, law, kpm, em, A);

    dim3 go(E_ / 64, M_ / 64, 1);
    out_gemm<<<go, 256, 0, stream>>>(A, Wo, bo, out);
}

// Round 4
// 256.175 us; speedup vs baseline: 1.7351x; 1.7351x over previous
//
#include <hip/hip_runtime.h>
#include <stdint.h>

#define T_ 256
#define B_ 8
#define E_ 512
#define H_ 32
#define HD_ 16
#define EXP_ 512
#define S_ 768          // T_ + EXP_
#define M_ 2048         // T_ * B_
#define SMOOTH_ 20.0f

// ---------------------------------------------------------------------------
// GEMM core (unchanged): C[m][n] = sum_e X[m][e] * W[n][e].
// ---------------------------------------------------------------------------
__device__ __forceinline__ void gemm_body(const float* __restrict__ X,
                                          const float* __restrict__ W,
                                          int m0, int n0,
                                          float acc[4][4],
                                          float* Xs, float* Ws)
{
    const int tid = threadIdx.x;
    const int lr  = tid >> 2;
    const int lc4 = tid & 3;
    const int tx  = tid & 15;
    const int ty  = tid >> 4;

    for (int k0 = 0; k0 < E_; k0 += 16) {
        float4 xv = *(const float4*)&X[(size_t)(m0 + lr) * E_ + k0 + lc4 * 4];
        float4 wv = *(const float4*)&W[(size_t)(n0 + lr) * E_ + k0 + lc4 * 4];
        __syncthreads();
        Xs[(lc4 * 4 + 0) * 64 + lr] = xv.x;
        Xs[(lc4 * 4 + 1) * 64 + lr] = xv.y;
        Xs[(lc4 * 4 + 2) * 64 + lr] = xv.z;
        Xs[(lc4 * 4 + 3) * 64 + lr] = xv.w;
        Ws[(lc4 * 4 + 0) * 64 + lr] = wv.x;
        Ws[(lc4 * 4 + 1) * 64 + lr] = wv.y;
        Ws[(lc4 * 4 + 2) * 64 + lr] = wv.z;
        Ws[(lc4 * 4 + 3) * 64 + lr] = wv.w;
        __syncthreads();
#pragma unroll
        for (int kk = 0; kk < 16; ++kk) {
            float4 a4 = *(const float4*)&Xs[kk * 64 + ty * 4];
            float4 b4 = *(const float4*)&Ws[kk * 64 + tx * 4];
            float a[4] = {a4.x, a4.y, a4.z, a4.w};
            float b[4] = {b4.x, b4.y, b4.z, b4.w};
#pragma unroll
            for (int i = 0; i < 4; ++i)
#pragma unroll
                for (int j = 0; j < 4; ++j)
                    acc[i][j] += a[i] * b[j];
        }
    }
}

__global__ __launch_bounds__(256)
void qkv_gemm(const float* __restrict__ X,
              const float* __restrict__ Wq, const float* __restrict__ bq,
              const float* __restrict__ Wk,
              const float* __restrict__ Wv, const float* __restrict__ bv,
              float* __restrict__ Q, float* __restrict__ K, float* __restrict__ V)
{
    __shared__ float Xs[16 * 64];
    __shared__ float Ws[16 * 64];
    const int z = blockIdx.z;
    const float* W    = (z == 0) ? Wq : (z == 1 ? Wk : Wv);
    const float* bias = (z == 0) ? bq : (z == 1 ? nullptr : bv);
    float* dst        = (z == 0) ? Q  : (z == 1 ? K  : V);
    const int rows    = (z == 0) ? T_ : S_;

    const int m0 = blockIdx.y * 64;
    const int n0 = blockIdx.x * 64;
    float acc[4][4] = {};
    gemm_body(X, W, m0, n0, acc, Xs, Ws);

    const int tx = threadIdx.x & 15;
    const int ty = threadIdx.x >> 4;
    float4 bias4 = make_float4(0.f, 0.f, 0.f, 0.f);
    if (bias) bias4 = *(const float4*)&bias[n0 + tx * 4];
#pragma unroll
    for (int i = 0; i < 4; ++i) {
        const int m = m0 + ty * 4 + i;
        const int t = m >> 3;
        const int b = m & 7;
        const int n = n0 + tx * 4;
        const int h = n >> 4;
        const int d = n & 15;
        float4 o;
        o.x = acc[i][0] + bias4.x;
        o.y = acc[i][1] + bias4.y;
        o.z = acc[i][2] + bias4.z;
        o.w = acc[i][3] + bias4.w;
        *(float4*)&dst[(((size_t)(b * H_ + h)) * rows + t) * HD_ + d] = o;
    }
}

__global__ __launch_bounds__(256)
void out_gemm(const float* __restrict__ X, const float* __restrict__ Wo,
              const float* __restrict__ bo, float* __restrict__ dst)
{
    __shared__ float Xs[16 * 64];
    __shared__ float Ws[16 * 64];
    const int m0 = blockIdx.y * 64;
    const int n0 = blockIdx.x * 64;
    float acc[4][4] = {};
    gemm_body(X, Wo, m0, n0, acc, Xs, Ws);

    const int tx = threadIdx.x & 15;
    const int ty = threadIdx.x >> 4;
    float4 bias4 = *(const float4*)&bo[n0 + tx * 4];
#pragma unroll
    for (int i = 0; i < 4; ++i) {
        const int m = m0 + ty * 4 + i;
        float4 o;
        o.x = acc[i][0] + bias4.x;
        o.y = acc[i][1] + bias4.y;
        o.z = acc[i][2] + bias4.z;
        o.w = acc[i][3] + bias4.w;
        *(float4*)&dst[(size_t)m * E_ + n0 + tx * 4] = o;
    }
}

// ---------------------------------------------------------------------------
// K/V expansion gather (unchanged).
// ---------------------------------------------------------------------------
__global__ __launch_bounds__(256)
void gather_kernel(const int* __restrict__ oc,
                   float* __restrict__ Kb, float* __restrict__ Vb)
{
    const int bj  = blockIdx.x;
    const int b   = bj >> 9;
    const int j   = bj & 511;
    const int src = oc[bj];

    const int tid   = threadIdx.x;
    const int which = tid >> 7;
    const int i     = tid & 127;
    const int h     = i >> 2;
    const int f4    = i & 3;
    float* P = which ? Vb : Kb;
    const float4* s4 = (const float4*)&P[(((size_t)(b * H_ + h)) * S_ + src) * HD_];
    float4*       d4 = (float4*)&P[(((size_t)(b * H_ + h)) * S_ + T_ + j) * HD_];
    d4[f4] = s4[f4];
}

// ---------------------------------------------------------------------------
// Attention v3: grid = (b,h) x 4 t-quarters (1024 blocks), 256 threads.
// Lane l owns row tq*64+l (q[16], acc[16], Z in registers -- round-2
// footprint, no spill). Wave w processes staged-tile rows [64w, 64w+64):
// all 64 lanes read the same K/V row from LDS (broadcast, conflict-free);
// the 4 waves jointly cover all s, so each thread does S/4 = 192 score+acc
// iterations. 4 blocks/CU x 4 waves = 4 waves/SIMD occupancy.
// Final: 4 waves' (acc, Z) partials combine through LDS aliased onto the
// staging buffers; combine parallelized as thread = (row, quad).
// Fixed-reference softmax: x in ~[-30,30] => exp(x-50) never over/underflows;
// scale cancels in acc/Z.
// ---------------------------------------------------------------------------
__global__ __launch_bounds__(256)
void attn_kernel(const float* __restrict__ Q, const float* __restrict__ Kb,
                 const float* __restrict__ Vb, const float* __restrict__ LAW,
                 const int* __restrict__ kpm, const int* __restrict__ em,
                 float* __restrict__ A)
{
    __shared__ float lds[8448];          // Ks[4096] | Vs[4096] | ms[256]
    float* Ks  = lds;
    float* Vs  = lds + 4096;
    int*   ms  = (int*)(lds + 8192);
    float* redA = lds;                   // alias: [w][row][16] = 4096 f
    float* redZ = lds + 4096;            // alias: [w][row]     = 256 f

    const int blk = blockIdx.x;
    const int bh  = blk >> 2;            // b*32+h
    const int tq  = blk & 3;
    const int b   = bh >> 5;
    const int h   = bh & 31;
    const int tid = threadIdx.x;
    const int w   = tid >> 6;            // wave 0..3 -> s-subset
    const int l   = tid & 63;
    const int row = tq * 64 + l;         // t index owned by this lane

    float q[16];
    {
        const float4* qp = (const float4*)&Q[((size_t)bh * T_ + row) * HD_];
#pragma unroll
        for (int i = 0; i < 4; ++i) {
            float4 v = qp[i];
            q[4 * i + 0] = v.x; q[4 * i + 1] = v.y;
            q[4 * i + 2] = v.z; q[4 * i + 3] = v.w;
        }
    }

    float acc[16] = {};
    float Z = 0.f;
    const float* lawp = &LAW[((size_t)b * T_ + row) * S_];

    for (int s0 = 0; s0 < S_; s0 += 256) {
        __syncthreads();
        {
            const float4* Kg = (const float4*)&Kb[((size_t)bh * S_ + s0) * HD_];
            const float4* Vg = (const float4*)&Vb[((size_t)bh * S_ + s0) * HD_];
            float4* Ks4 = (float4*)Ks;
            float4* Vs4 = (float4*)Vs;
#pragma unroll
            for (int i = 0; i < 4; ++i) {
                Ks4[tid + 256 * i] = Kg[tid + 256 * i];
                Vs4[tid + 256 * i] = Vg[tid + 256 * i];
            }
            const int s = s0 + tid;
            ms[tid] = (s < T_) ? kpm[b * T_ + s] : em[b * EXP_ + (s - T_)];
        }
        __syncthreads();

        for (int j = 0; j < 16; ++j) {
            const int rbase = w * 64 + j * 4;
            float4 lw = *(const float4*)&lawp[s0 + rbase];
            float lwa[4] = {lw.x, lw.y, lw.z, lw.w};
#pragma unroll
            for (int u = 0; u < 4; ++u) {
                const int r = rbase + u;
                const float4* kr = (const float4*)&Ks[r * 16];
                float4 ka = kr[0], kb4 = kr[1], kc = kr[2], kd = kr[3];
                float p0 = q[0] * ka.x  + q[1] * ka.y  + q[2] * ka.z  + q[3] * ka.w;
                float p1 = q[4] * kb4.x + q[5] * kb4.y + q[6] * kb4.z + q[7] * kb4.w;
                float p2 = q[8] * kc.x  + q[9] * kc.y  + q[10] * kc.z + q[11] * kc.w;
                float p3 = q[12] * kd.x + q[13] * kd.y + q[14] * kd.z + q[15] * kd.w;
                const float sc = (p0 + p1) + (p2 + p3);
                const float x  = (sc + SMOOTH_) * lwa[u] - SMOOTH_;
                const float e  = ms[r] ? 0.f : __expf(x - 50.f);
                Z += e;
                const float wgt = e * lwa[u];
                const float4* vr = (const float4*)&Vs[r * 16];
#pragma unroll
                for (int i = 0; i < 4; ++i) {
                    float4 vv = vr[i];
                    acc[4 * i + 0] += wgt * vv.x;
                    acc[4 * i + 1] += wgt * vv.y;
                    acc[4 * i + 2] += wgt * vv.z;
                    acc[4 * i + 3] += wgt * vv.w;
                }
            }
        }
    }

    __syncthreads();   // staging LDS free; alias as reduction buffer

    {
        float4* ra = (float4*)&redA[(size_t)tid * 16];   // tid = w*64+l
#pragma unroll
        for (int i = 0; i < 4; ++i)
            ra[i] = make_float4(acc[4 * i], acc[4 * i + 1],
                                acc[4 * i + 2], acc[4 * i + 3]);
        redZ[tid] = Z;
    }
    __syncthreads();

    {
        const int r2 = tid >> 2;        // local row 0..63
        const int qd = tid & 3;         // quad 0..3
        float Zt = redZ[r2] + redZ[64 + r2] + redZ[128 + r2] + redZ[192 + r2];
        float4 s0v = *(const float4*)&redA[((size_t)r2) * 16 + qd * 4];
        float4 s1v = *(const float4*)&redA[((size_t)(64 + r2)) * 16 + qd * 4];
        float4 s2v = *(const float4*)&redA[((size_t)(128 + r2)) * 16 + qd * 4];
        float4 s3v = *(const float4*)&redA[((size_t)(192 + r2)) * 16 + qd * 4];
        const float inv = (Zt > 0.f) ? 1.f / Zt : 0.f;
        float4 o;
        o.x = (s0v.x + s1v.x + s2v.x + s3v.x) * inv;
        o.y = (s0v.y + s1v.y + s2v.y + s3v.y) * inv;
        o.z = (s0v.z + s1v.z + s2v.z + s3v.z) * inv;
        o.w = (s0v.w + s1v.w + s2v.w + s3v.w) * inv;
        const int trow = tq * 64 + r2;
        *(float4*)&A[(((size_t)trow * B_) + b) * E_ + h * HD_ + qd * 4] = o;
    }
}

// ---------------------------------------------------------------------------
extern "C" void kernel_launch(void* const* d_in, const int* in_sizes, int n_in,
                              void* d_out, int out_size, void* d_ws, size_t ws_size,
                              hipStream_t stream)
{
    const float* query = (const float*)d_in[0];
    const int*   oc    = (const int*)d_in[1];
    const int*   em    = (const int*)d_in[2];
    const int*   kpm   = (const int*)d_in[3];
    const float* law   = (const float*)d_in[4];
    const float* Wq    = (const float*)d_in[5];
    const float* bq    = (const float*)d_in[6];
    const float* Wk    = (const float*)d_in[7];
    const float* Wv    = (const float*)d_in[8];
    const float* bv    = (const float*)d_in[9];
    const float* Wo    = (const float*)d_in[10];
    const float* bo    = (const float*)d_in[11];
    float* out = (float*)d_out;

    float* ws = (float*)d_ws;
    float* Q = ws;                       // [B][H][T][16]
    float* K = Q + (size_t)1048576;      // [B][H][S][16]
    float* V = K + (size_t)3145728;      // [B][H][S][16]
    float* A = V + (size_t)3145728;      // [t][b][e]

    dim3 gq(E_ / 64, M_ / 64, 3);
    qkv_gemm<<<gq, 256, 0, stream>>>(query, Wq, bq, Wk, Wv, bv, Q, K, V);

    gather_kernel<<<B_ * EXP_, 256, 0, stream>>>(oc, K, V);

    attn_kernel<<<B_ * H_ * 4, 256, 0, stream>>>(Q, K, V, law, kpm, em, A);

    dim3 go(E_ / 64, M_ / 64, 1);
    out_gemm<<<go, 256, 0, stream>>>(A, Wo, bo, out);
}

// Round 5
// 208.858 us; speedup vs baseline: 2.1282x; 1.2266x over previous
//
#include <hip/hip_runtime.h>
#include <stdint.h>

#define T_ 256
#define B_ 8
#define E_ 512
#define H_ 32
#define HD_ 16
#define EXP_ 512
#define S_ 768          // T_ + EXP_
#define M_ 2048         // T_ * B_
#define SMOOTH_ 20.0f

typedef __attribute__((ext_vector_type(8))) short bf16x8;
typedef __attribute__((ext_vector_type(4))) float f32x4;

// RNE pack: two fp32 -> one dword holding two bf16 (lo = a, hi = b)
__device__ __forceinline__ unsigned int pk2(float a, float b)
{
    unsigned int ua = __float_as_uint(a);
    ua = ua + 0x7FFFu + ((ua >> 16) & 1u);
    unsigned int ub = __float_as_uint(b);
    ub = ub + 0x7FFFu + ((ub >> 16) & 1u);
    return (ua >> 16) | (ub & 0xFFFF0000u);
}

// ---------------------------------------------------------------------------
// MFMA GEMM: C[m][n] = sum_k X[m][k] * W[n][k]  (both row-major, k contig).
// 64x64 block tile, 256 threads = 4 waves, wave (wm,wn) computes 32x32 via
// 2x2 mfma_f32_16x16x32_bf16 subtiles. BK=64, fp32->bf16 conversion fused
// into LDS staging. A/B frag: lane holds row (lane&15)+16i, k = (lane>>4)*8
// + j (verified layout, learn_hip m89/m92). C/D: col=lane&15,
// row=(lane>>4)*4+reg (m89/m91).
// LDS row stride 72 bf16 = 144 B (16-B aligned for b128 ops).
// ---------------------------------------------------------------------------
struct GemmFrags { f32x4 acc[2][2]; };

__device__ __forceinline__ void mfma_gemm_body(const float* __restrict__ X,
                                               const float* __restrict__ W,
                                               int m0, int n0,
                                               f32x4 acc[2][2],
                                               ushort* As, ushort* Bs)
{
    const int tid  = threadIdx.x;
    const int lrow = tid >> 2;      // 0..63 staged row
    const int kq   = tid & 3;       // 16-k chunk
    const int l    = tid & 63;
    const int w    = tid >> 6;
    const int wm   = w & 1;
    const int wn   = w >> 1;
    const int lq   = l >> 4;        // 0..3
    const int ln   = l & 15;

    const float* Xr = &X[(size_t)(m0 + lrow) * E_ + kq * 16];
    const float* Wr = &W[(size_t)(n0 + lrow) * E_ + kq * 16];
    ushort* Aw = &As[lrow * 72 + kq * 16];
    ushort* Bw = &Bs[lrow * 72 + kq * 16];

    for (int k0 = 0; k0 < E_; k0 += 64) {
        float4 a0 = *(const float4*)&Xr[k0 + 0];
        float4 a1 = *(const float4*)&Xr[k0 + 4];
        float4 a2 = *(const float4*)&Xr[k0 + 8];
        float4 a3 = *(const float4*)&Xr[k0 + 12];
        float4 b0 = *(const float4*)&Wr[k0 + 0];
        float4 b1 = *(const float4*)&Wr[k0 + 4];
        float4 b2 = *(const float4*)&Wr[k0 + 8];
        float4 b3 = *(const float4*)&Wr[k0 + 12];

        uint4 ua0 = make_uint4(pk2(a0.x, a0.y), pk2(a0.z, a0.w),
                               pk2(a1.x, a1.y), pk2(a1.z, a1.w));
        uint4 ua1 = make_uint4(pk2(a2.x, a2.y), pk2(a2.z, a2.w),
                               pk2(a3.x, a3.y), pk2(a3.z, a3.w));
        uint4 ub0 = make_uint4(pk2(b0.x, b0.y), pk2(b0.z, b0.w),
                               pk2(b1.x, b1.y), pk2(b1.z, b1.w));
        uint4 ub1 = make_uint4(pk2(b2.x, b2.y), pk2(b2.z, b2.w),
                               pk2(b3.x, b3.y), pk2(b3.z, b3.w));

        __syncthreads();
        *(uint4*)&Aw[0] = ua0;
        *(uint4*)&Aw[8] = ua1;
        *(uint4*)&Bw[0] = ub0;
        *(uint4*)&Bw[8] = ub1;
        __syncthreads();

#pragma unroll
        for (int kb = 0; kb < 2; ++kb) {
            bf16x8 af0 = *(const bf16x8*)&As[(32 * wm + ln) * 72 + 32 * kb + lq * 8];
            bf16x8 af1 = *(const bf16x8*)&As[(32 * wm + 16 + ln) * 72 + 32 * kb + lq * 8];
            bf16x8 bf0 = *(const bf16x8*)&Bs[(32 * wn + ln) * 72 + 32 * kb + lq * 8];
            bf16x8 bf1 = *(const bf16x8*)&Bs[(32 * wn + 16 + ln) * 72 + 32 * kb + lq * 8];
            acc[0][0] = __builtin_amdgcn_mfma_f32_16x16x32_bf16(af0, bf0, acc[0][0], 0, 0, 0);
            acc[0][1] = __builtin_amdgcn_mfma_f32_16x16x32_bf16(af0, bf1, acc[0][1], 0, 0, 0);
            acc[1][0] = __builtin_amdgcn_mfma_f32_16x16x32_bf16(af1, bf0, acc[1][0], 0, 0, 0);
            acc[1][1] = __builtin_amdgcn_mfma_f32_16x16x32_bf16(af1, bf1, acc[1][1], 0, 0, 0);
        }
    }
}

__global__ __launch_bounds__(256)
void qkv_gemm(const float* __restrict__ X,
              const float* __restrict__ Wq, const float* __restrict__ bq,
              const float* __restrict__ Wk,
              const float* __restrict__ Wv, const float* __restrict__ bv,
              float* __restrict__ Q, float* __restrict__ K, float* __restrict__ V)
{
    __shared__ __align__(16) ushort As[64 * 72];
    __shared__ __align__(16) ushort Bs[64 * 72];
    const int z = blockIdx.z;
    const float* W    = (z == 0) ? Wq : (z == 1 ? Wk : Wv);
    const float* bias = (z == 0) ? bq : (z == 1 ? nullptr : bv);
    float* dst        = (z == 0) ? Q  : (z == 1 ? K  : V);
    const int rows    = (z == 0) ? T_ : S_;

    const int m0 = blockIdx.y * 64;
    const int n0 = blockIdx.x * 64;

    f32x4 acc[2][2];
#pragma unroll
    for (int i = 0; i < 2; ++i)
#pragma unroll
        for (int j = 0; j < 2; ++j)
            acc[i][j] = (f32x4){0.f, 0.f, 0.f, 0.f};

    mfma_gemm_body(X, W, m0, n0, acc, As, Bs);

    const int l  = threadIdx.x & 63;
    const int w  = threadIdx.x >> 6;
    const int wm = w & 1;
    const int wn = w >> 1;
    const int lq = l >> 4;
    const int ln = l & 15;

#pragma unroll
    for (int j = 0; j < 2; ++j) {
        const int nb = n0 + 32 * wn + 16 * j;   // multiple of 16
        const int h  = nb >> 4;
        const float bv_ = bias ? bias[nb + ln] : 0.f;
#pragma unroll
        for (int i = 0; i < 2; ++i) {
#pragma unroll
            for (int r = 0; r < 4; ++r) {
                const int m = m0 + 32 * wm + 16 * i + lq * 4 + r;
                const int t = m >> 3;
                const int b = m & 7;
                dst[(((size_t)(b * H_ + h)) * rows + t) * HD_ + ln] = acc[i][j][r] + bv_;
            }
        }
    }
}

__global__ __launch_bounds__(256)
void out_gemm(const float* __restrict__ X, const float* __restrict__ Wo,
              const float* __restrict__ bo, float* __restrict__ dst)
{
    __shared__ __align__(16) ushort As[64 * 72];
    __shared__ __align__(16) ushort Bs[64 * 72];
    const int m0 = blockIdx.y * 64;
    const int n0 = blockIdx.x * 64;

    f32x4 acc[2][2];
#pragma unroll
    for (int i = 0; i < 2; ++i)
#pragma unroll
        for (int j = 0; j < 2; ++j)
            acc[i][j] = (f32x4){0.f, 0.f, 0.f, 0.f};

    mfma_gemm_body(X, Wo, m0, n0, acc, As, Bs);

    const int l  = threadIdx.x & 63;
    const int w  = threadIdx.x >> 6;
    const int wm = w & 1;
    const int wn = w >> 1;
    const int lq = l >> 4;
    const int ln = l & 15;

#pragma unroll
    for (int j = 0; j < 2; ++j) {
        const int nb = n0 + 32 * wn + 16 * j;
        const float bo_ = bo[nb + ln];
#pragma unroll
        for (int i = 0; i < 2; ++i) {
#pragma unroll
            for (int r = 0; r < 4; ++r) {
                const int m = m0 + 32 * wm + 16 * i + lq * 4 + r;
                dst[(size_t)m * E_ + nb + ln] = acc[i][j][r] + bo_;
            }
        }
    }
}

// ---------------------------------------------------------------------------
// K/V expansion gather (unchanged).
// ---------------------------------------------------------------------------
__global__ __launch_bounds__(256)
void gather_kernel(const int* __restrict__ oc,
                   float* __restrict__ Kb, float* __restrict__ Vb)
{
    const int bj  = blockIdx.x;
    const int b   = bj >> 9;
    const int j   = bj & 511;
    const int src = oc[bj];

    const int tid   = threadIdx.x;
    const int which = tid >> 7;
    const int i     = tid & 127;
    const int h     = i >> 2;
    const int f4    = i & 3;
    float* P = which ? Vb : Kb;
    const float4* s4 = (const float4*)&P[(((size_t)(b * H_ + h)) * S_ + src) * HD_];
    float4*       d4 = (float4*)&P[(((size_t)(b * H_ + h)) * S_ + T_ + j) * HD_];
    d4[f4] = s4[f4];
}

// ---------------------------------------------------------------------------
// Attention v3 (unchanged from round 4): grid = (b,h) x 4 t-quarters,
// 256 threads; lane owns one t-row, wave covers 1/4 of s; LDS-staged K/V
// broadcast reads; fixed-reference softmax; 4-wave partial combine via LDS.
// ---------------------------------------------------------------------------
__global__ __launch_bounds__(256)
void attn_kernel(const float* __restrict__ Q, const float* __restrict__ Kb,
                 const float* __restrict__ Vb, const float* __restrict__ LAW,
                 const int* __restrict__ kpm, const int* __restrict__ em,
                 float* __restrict__ A)
{
    __shared__ float lds[8448];          // Ks[4096] | Vs[4096] | ms[256]
    float* Ks  = lds;
    float* Vs  = lds + 4096;
    int*   ms  = (int*)(lds + 8192);
    float* redA = lds;                   // alias after compute
    float* redZ = lds + 4096;

    const int blk = blockIdx.x;
    const int bh  = blk >> 2;
    const int tq  = blk & 3;
    const int b   = bh >> 5;
    const int h   = bh & 31;
    const int tid = threadIdx.x;
    const int w   = tid >> 6;
    const int l   = tid & 63;
    const int row = tq * 64 + l;

    float q[16];
    {
        const float4* qp = (const float4*)&Q[((size_t)bh * T_ + row) * HD_];
#pragma unroll
        for (int i = 0; i < 4; ++i) {
            float4 v = qp[i];
            q[4 * i + 0] = v.x; q[4 * i + 1] = v.y;
            q[4 * i + 2] = v.z; q[4 * i + 3] = v.w;
        }
    }

    float acc[16] = {};
    float Z = 0.f;
    const float* lawp = &LAW[((size_t)b * T_ + row) * S_];

    for (int s0 = 0; s0 < S_; s0 += 256) {
        __syncthreads();
        {
            const float4* Kg = (const float4*)&Kb[((size_t)bh * S_ + s0) * HD_];
            const float4* Vg = (const float4*)&Vb[((size_t)bh * S_ + s0) * HD_];
            float4* Ks4 = (float4*)Ks;
            float4* Vs4 = (float4*)Vs;
#pragma unroll
            for (int i = 0; i < 4; ++i) {
                Ks4[tid + 256 * i] = Kg[tid + 256 * i];
                Vs4[tid + 256 * i] = Vg[tid + 256 * i];
            }
            const int s = s0 + tid;
            ms[tid] = (s < T_) ? kpm[b * T_ + s] : em[b * EXP_ + (s - T_)];
        }
        __syncthreads();

        for (int j = 0; j < 16; ++j) {
            const int rbase = w * 64 + j * 4;
            float4 lw = *(const float4*)&lawp[s0 + rbase];
            float lwa[4] = {lw.x, lw.y, lw.z, lw.w};
#pragma unroll
            for (int u = 0; u < 4; ++u) {
                const int r = rbase + u;
                const float4* kr = (const float4*)&Ks[r * 16];
                float4 ka = kr[0], kb4 = kr[1], kc = kr[2], kd = kr[3];
                float p0 = q[0] * ka.x  + q[1] * ka.y  + q[2] * ka.z  + q[3] * ka.w;
                float p1 = q[4] * kb4.x + q[5] * kb4.y + q[6] * kb4.z + q[7] * kb4.w;
                float p2 = q[8] * kc.x  + q[9] * kc.y  + q[10] * kc.z + q[11] * kc.w;
                float p3 = q[12] * kd.x + q[13] * kd.y + q[14] * kd.z + q[15] * kd.w;
                const float sc = (p0 + p1) + (p2 + p3);
                const float x  = (sc + SMOOTH_) * lwa[u] - SMOOTH_;
                const float e  = ms[r] ? 0.f : __expf(x - 50.f);
                Z += e;
                const float wgt = e * lwa[u];
                const float4* vr = (const float4*)&Vs[r * 16];
#pragma unroll
                for (int i = 0; i < 4; ++i) {
                    float4 vv = vr[i];
                    acc[4 * i + 0] += wgt * vv.x;
                    acc[4 * i + 1] += wgt * vv.y;
                    acc[4 * i + 2] += wgt * vv.z;
                    acc[4 * i + 3] += wgt * vv.w;
                }
            }
        }
    }

    __syncthreads();

    {
        float4* ra = (float4*)&redA[(size_t)tid * 16];
#pragma unroll
        for (int i = 0; i < 4; ++i)
            ra[i] = make_float4(acc[4 * i], acc[4 * i + 1],
                                acc[4 * i + 2], acc[4 * i + 3]);
        redZ[tid] = Z;
    }
    __syncthreads();

    {
        const int r2 = tid >> 2;
        const int qd = tid & 3;
        float Zt = redZ[r2] + redZ[64 + r2] + redZ[128 + r2] + redZ[192 + r2];
        float4 s0v = *(const float4*)&redA[((size_t)r2) * 16 + qd * 4];
        float4 s1v = *(const float4*)&redA[((size_t)(64 + r2)) * 16 + qd * 4];
        float4 s2v = *(const float4*)&redA[((size_t)(128 + r2)) * 16 + qd * 4];
        float4 s3v = *(const float4*)&redA[((size_t)(192 + r2)) * 16 + qd * 4];
        const float inv = (Zt > 0.f) ? 1.f / Zt : 0.f;
        float4 o;
        o.x = (s0v.x + s1v.x + s2v.x + s3v.x) * inv;
        o.y = (s0v.y + s1v.y + s2v.y + s3v.y) * inv;
        o.z = (s0v.z + s1v.z + s2v.z + s3v.z) * inv;
        o.w = (s0v.w + s1v.w + s2v.w + s3v.w) * inv;
        const int trow = tq * 64 + r2;
        *(float4*)&A[(((size_t)trow * B_) + b) * E_ + h * HD_ + qd * 4] = o;
    }
}

// ---------------------------------------------------------------------------
extern "C" void kernel_launch(void* const* d_in, const int* in_sizes, int n_in,
                              void* d_out, int out_size, void* d_ws, size_t ws_size,
                              hipStream_t stream)
{
    const float* query = (const float*)d_in[0];
    const int*   oc    = (const int*)d_in[1];
    const int*   em    = (const int*)d_in[2];
    const int*   kpm   = (const int*)d_in[3];
    const float* law   = (const float*)d_in[4];
    const float* Wq    = (const float*)d_in[5];
    const float* bq    = (const float*)d_in[6];
    const float* Wk    = (const float*)d_in[7];
    const float* Wv    = (const float*)d_in[8];
    const float* bv    = (const float*)d_in[9];
    const float* Wo    = (const float*)d_in[10];
    const float* bo    = (const float*)d_in[11];
    float* out = (float*)d_out;

    float* ws = (float*)d_ws;
    float* Q = ws;                       // [B][H][T][16]
    float* K = Q + (size_t)1048576;      // [B][H][S][16]
    float* V = K + (size_t)3145728;      // [B][H][S][16]
    float* A = V + (size_t)3145728;      // [t][b][e]

    dim3 gq(E_ / 64, M_ / 64, 3);
    qkv_gemm<<<gq, 256, 0, stream>>>(query, Wq, bq, Wk, Wv, bv, Q, K, V);

    gather_kernel<<<B_ * EXP_, 256, 0, stream>>>(oc, K, V);

    attn_kernel<<<B_ * H_ * 4, 256, 0, stream>>>(Q, K, V, law, kpm, em, A);

    dim3 go(E_ / 64, M_ / 64, 1);
    out_gemm<<<go, 256, 0, stream>>>(A, Wo, bo, out);
}

// Round 6
// 149.809 us; speedup vs baseline: 2.9670x; 1.3942x over previous
//
#include <hip/hip_runtime.h>
#include <stdint.h>

#define T_ 256
#define B_ 8
#define E_ 512
#define H_ 32
#define HD_ 16
#define EXP_ 512
#define S_ 768          // T_ + EXP_
#define M_ 2048         // T_ * B_
#define SMOOTH_ 20.0f
#define PSTR 36         // P-tile LDS row stride (bf16 elems); 36 -> <=4-way banks
#define VSTR 800        // V^T LDS row stride (bf16 elems); 16B-aligned rows

typedef __attribute__((ext_vector_type(8)))  short bf16x8;
typedef __attribute__((ext_vector_type(4)))  float f32x4;
typedef __attribute__((ext_vector_type(16))) float f32x16;

// RNE pack: two fp32 -> one dword of two bf16 (lo=a, hi=b)
__device__ __forceinline__ unsigned int pk2(float a, float b)
{
    unsigned int ua = __float_as_uint(a);
    ua = ua + 0x7FFFu + ((ua >> 16) & 1u);
    unsigned int ub = __float_as_uint(b);
    ub = ub + 0x7FFFu + ((ub >> 16) & 1u);
    return (ua >> 16) | (ub & 0xFFFF0000u);
}
__device__ __forceinline__ ushort bf1(float a)
{
    unsigned int u = __float_as_uint(a);
    u = u + 0x7FFFu + ((u >> 16) & 1u);
    return (ushort)(u >> 16);
}

union U16 { uint4 u; bf16x8 v; };

// ---------------------------------------------------------------------------
// MFMA GEMM (unchanged from round 5): C[m][n] = sum_k X[m][k] * W[n][k].
// ---------------------------------------------------------------------------
__device__ __forceinline__ void mfma_gemm_body(const float* __restrict__ X,
                                               const float* __restrict__ W,
                                               int m0, int n0,
                                               f32x4 acc[2][2],
                                               ushort* As, ushort* Bs)
{
    const int tid  = threadIdx.x;
    const int lrow = tid >> 2;
    const int kq   = tid & 3;
    const int l    = tid & 63;
    const int w    = tid >> 6;
    const int wm   = w & 1;
    const int wn   = w >> 1;
    const int lq   = l >> 4;
    const int ln   = l & 15;

    const float* Xr = &X[(size_t)(m0 + lrow) * E_ + kq * 16];
    const float* Wr = &W[(size_t)(n0 + lrow) * E_ + kq * 16];
    ushort* Aw = &As[lrow * 72 + kq * 16];
    ushort* Bw = &Bs[lrow * 72 + kq * 16];

    for (int k0 = 0; k0 < E_; k0 += 64) {
        float4 a0 = *(const float4*)&Xr[k0 + 0];
        float4 a1 = *(const float4*)&Xr[k0 + 4];
        float4 a2 = *(const float4*)&Xr[k0 + 8];
        float4 a3 = *(const float4*)&Xr[k0 + 12];
        float4 b0 = *(const float4*)&Wr[k0 + 0];
        float4 b1 = *(const float4*)&Wr[k0 + 4];
        float4 b2 = *(const float4*)&Wr[k0 + 8];
        float4 b3 = *(const float4*)&Wr[k0 + 12];

        uint4 ua0 = make_uint4(pk2(a0.x, a0.y), pk2(a0.z, a0.w),
                               pk2(a1.x, a1.y), pk2(a1.z, a1.w));
        uint4 ua1 = make_uint4(pk2(a2.x, a2.y), pk2(a2.z, a2.w),
                               pk2(a3.x, a3.y), pk2(a3.z, a3.w));
        uint4 ub0 = make_uint4(pk2(b0.x, b0.y), pk2(b0.z, b0.w),
                               pk2(b1.x, b1.y), pk2(b1.z, b1.w));
        uint4 ub1 = make_uint4(pk2(b2.x, b2.y), pk2(b2.z, b2.w),
                               pk2(b3.x, b3.y), pk2(b3.z, b3.w));

        __syncthreads();
        *(uint4*)&Aw[0] = ua0;
        *(uint4*)&Aw[8] = ua1;
        *(uint4*)&Bw[0] = ub0;
        *(uint4*)&Bw[8] = ub1;
        __syncthreads();

#pragma unroll
        for (int kb = 0; kb < 2; ++kb) {
            bf16x8 af0 = *(const bf16x8*)&As[(32 * wm + ln) * 72 + 32 * kb + lq * 8];
            bf16x8 af1 = *(const bf16x8*)&As[(32 * wm + 16 + ln) * 72 + 32 * kb + lq * 8];
            bf16x8 bf0 = *(const bf16x8*)&Bs[(32 * wn + ln) * 72 + 32 * kb + lq * 8];
            bf16x8 bf1 = *(const bf16x8*)&Bs[(32 * wn + 16 + ln) * 72 + 32 * kb + lq * 8];
            acc[0][0] = __builtin_amdgcn_mfma_f32_16x16x32_bf16(af0, bf0, acc[0][0], 0, 0, 0);
            acc[0][1] = __builtin_amdgcn_mfma_f32_16x16x32_bf16(af0, bf1, acc[0][1], 0, 0, 0);
            acc[1][0] = __builtin_amdgcn_mfma_f32_16x16x32_bf16(af1, bf0, acc[1][0], 0, 0, 0);
            acc[1][1] = __builtin_amdgcn_mfma_f32_16x16x32_bf16(af1, bf1, acc[1][1], 0, 0, 0);
        }
    }
}

__global__ __launch_bounds__(256)
void qkv_gemm(const float* __restrict__ X,
              const float* __restrict__ Wq, const float* __restrict__ bq,
              const float* __restrict__ Wk,
              const float* __restrict__ Wv, const float* __restrict__ bv,
              float* __restrict__ Q, float* __restrict__ K, float* __restrict__ V)
{
    __shared__ __align__(16) ushort As[64 * 72];
    __shared__ __align__(16) ushort Bs[64 * 72];
    const int z = blockIdx.z;
    const float* W    = (z == 0) ? Wq : (z == 1 ? Wk : Wv);
    const float* bias = (z == 0) ? bq : (z == 1 ? nullptr : bv);
    float* dst        = (z == 0) ? Q  : (z == 1 ? K  : V);
    const int rows    = (z == 0) ? T_ : S_;

    const int m0 = blockIdx.y * 64;
    const int n0 = blockIdx.x * 64;

    f32x4 acc[2][2];
#pragma unroll
    for (int i = 0; i < 2; ++i)
#pragma unroll
        for (int j = 0; j < 2; ++j)
            acc[i][j] = (f32x4){0.f, 0.f, 0.f, 0.f};

    mfma_gemm_body(X, W, m0, n0, acc, As, Bs);

    const int l  = threadIdx.x & 63;
    const int w  = threadIdx.x >> 6;
    const int wm = w & 1;
    const int wn = w >> 1;
    const int lq = l >> 4;
    const int ln = l & 15;

#pragma unroll
    for (int j = 0; j < 2; ++j) {
        const int nb = n0 + 32 * wn + 16 * j;
        const int h  = nb >> 4;
        const float bv_ = bias ? bias[nb + ln] : 0.f;
#pragma unroll
        for (int i = 0; i < 2; ++i) {
#pragma unroll
            for (int r = 0; r < 4; ++r) {
                const int m = m0 + 32 * wm + 16 * i + lq * 4 + r;
                const int t = m >> 3;
                const int b = m & 7;
                dst[(((size_t)(b * H_ + h)) * rows + t) * HD_ + ln] = acc[i][j][r] + bv_;
            }
        }
    }
}

__global__ __launch_bounds__(256)
void out_gemm(const float* __restrict__ X, const float* __restrict__ Wo,
              const float* __restrict__ bo, float* __restrict__ dst)
{
    __shared__ __align__(16) ushort As[64 * 72];
    __shared__ __align__(16) ushort Bs[64 * 72];
    const int m0 = blockIdx.y * 64;
    const int n0 = blockIdx.x * 64;

    f32x4 acc[2][2];
#pragma unroll
    for (int i = 0; i < 2; ++i)
#pragma unroll
        for (int j = 0; j < 2; ++j)
            acc[i][j] = (f32x4){0.f, 0.f, 0.f, 0.f};

    mfma_gemm_body(X, Wo, m0, n0, acc, As, Bs);

    const int l  = threadIdx.x & 63;
    const int w  = threadIdx.x >> 6;
    const int wm = w & 1;
    const int wn = w >> 1;
    const int lq = l >> 4;
    const int ln = l & 15;

#pragma unroll
    for (int j = 0; j < 2; ++j) {
        const int nb = n0 + 32 * wn + 16 * j;
        const float bo_ = bo[nb + ln];
#pragma unroll
        for (int i = 0; i < 2; ++i) {
#pragma unroll
            for (int r = 0; r < 4; ++r) {
                const int m = m0 + 32 * wm + 16 * i + lq * 4 + r;
                dst[(size_t)m * E_ + nb + ln] = acc[i][j][r] + bo_;
            }
        }
    }
}

// ---------------------------------------------------------------------------
// K/V expansion gather (unchanged).
// ---------------------------------------------------------------------------
__global__ __launch_bounds__(256)
void gather_kernel(const int* __restrict__ oc,
                   float* __restrict__ Kb, float* __restrict__ Vb)
{
    const int bj  = blockIdx.x;
    const int b   = bj >> 9;
    const int j   = bj & 511;
    const int src = oc[bj];

    const int tid   = threadIdx.x;
    const int which = tid >> 7;
    const int i     = tid & 127;
    const int h     = i >> 2;
    const int f4    = i & 3;
    float* P = which ? Vb : Kb;
    const float4* s4 = (const float4*)&P[(((size_t)(b * H_ + h)) * S_ + src) * HD_];
    float4*       d4 = (float4*)&P[(((size_t)(b * H_ + h)) * S_ + T_ + j) * HD_];
    d4[f4] = s4[f4];
}

// ---------------------------------------------------------------------------
// Attention v4 (MFMA): block = (b,h) x t-half, 256 threads = 4 waves,
// wave owns one 32-row t-tile. Stage K bf16 [s][16], V^T bf16 [16][VSTR],
// mask-as-float msf[768] once; then a barrier-free s-loop:
//   S^T tile = mfma_32x32x16(Kfrag, Qfrag)  -> lanes = t, regs = s
//   softmax (fixed-ref exp, Z = in-reg sum), P = e*law packed bf16 -> LDS
//   O^T += mfma_16x16x32(V^Tfrag, Pfrag)    -> lanes = t, regs = d
// Z finalized with one shfl_xor(32); divide in epilogue.
// ---------------------------------------------------------------------------
__global__ __launch_bounds__(256)
void attn_kernel(const float* __restrict__ Q, const float* __restrict__ Kb,
                 const float* __restrict__ Vb, const float* __restrict__ LAW,
                 const int* __restrict__ kpm, const int* __restrict__ em,
                 float* __restrict__ A)
{
    __shared__ __align__(16) ushort Ks[S_ * HD_];       // 24576 B
    __shared__ __align__(16) ushort Vt[HD_ * VSTR];     // 25600 B
    __shared__ __align__(16) float  msf[S_];            // 3072 B
    __shared__ __align__(16) float  Zbuf[128];          // 512 B
    __shared__ __align__(16) ushort Pb[4][32 * PSTR];   // 9216 B  (total ~63KB)

    const int tid    = threadIdx.x;
    const int blk    = blockIdx.x;
    const int bh     = blk >> 1;
    const int thalf  = blk & 1;
    const int b      = bh >> 5;
    const int h      = bh & 31;

    // ---- stage K as bf16 (contiguous image) ----
    {
        const float4* src = (const float4*)&Kb[(size_t)bh * S_ * HD_];
        for (int f = tid; f < S_ * HD_ / 4; f += 256) {
            float4 v = src[f];
            *(uint2*)&Ks[f * 4] = make_uint2(pk2(v.x, v.y), pk2(v.z, v.w));
        }
    }
    // ---- stage V^T as bf16 ----
    for (int s = tid; s < S_; s += 256) {
        const float* vr = &Vb[((size_t)bh * S_ + s) * HD_];
#pragma unroll
        for (int d = 0; d < 16; ++d)
            Vt[d * VSTR + s] = bf1(vr[d]);
    }
    // ---- mask as float ----
    for (int s = tid; s < S_; s += 256) {
        int m = (s < T_) ? kpm[b * T_ + s] : em[b * EXP_ + (s - T_)];
        msf[s] = m ? 0.f : 1.f;
    }

    // ---- Q fragment (B operand of S^T MFMA: n=t on lanes, k=hd) ----
    const int w      = tid >> 6;
    const int l      = tid & 63;
    const int tloc   = l & 31;
    const int khalf  = l >> 5;
    const int tglob  = thalf * 128 + w * 32 + tloc;
    bf16x8 qf;
    {
        const float* qp = &Q[((size_t)bh * T_ + tglob) * HD_ + khalf * 8];
        float4 q0 = *(const float4*)qp;
        float4 q1 = *(const float4*)(qp + 4);
        U16 u;
        u.u = make_uint4(pk2(q0.x, q0.y), pk2(q0.z, q0.w),
                         pk2(q1.x, q1.y), pk2(q1.z, q1.w));
        qf = u.v;
    }

    __syncthreads();

    const f32x16 zero16 = {0.f,0.f,0.f,0.f,0.f,0.f,0.f,0.f,
                           0.f,0.f,0.f,0.f,0.f,0.f,0.f,0.f};
    f32x4 o0 = {0.f, 0.f, 0.f, 0.f};
    f32x4 o1 = {0.f, 0.f, 0.f, 0.f};
    float Z = 0.f;

    const float* lawp = &LAW[((size_t)b * T_ + tglob) * S_];
    ushort* prow = &Pb[w][tloc * PSTR];
    const int tl = l & 15;
    const int kg = l >> 4;

    for (int i = 0; i < S_ / 32; ++i) {
        // K A-frag: m=s on lanes, k=hd
        bf16x8 kf = *(const bf16x8*)&Ks[(i * 32 + tloc) * HD_ + khalf * 8];
        f32x16 sc = __builtin_amdgcn_mfma_f32_32x32x16_bf16(kf, qf, zero16, 0, 0, 0);

        // law + msf quads: s_loc = u + 8*qd + 4*khalf  == C/D row pattern
#pragma unroll
        for (int qd = 0; qd < 4; ++qd) {
            const int sb = i * 32 + qd * 8 + khalf * 4;
            float4 mf = *(const float4*)&msf[sb];
            float4 lw = *(const float4*)&lawp[sb];
            float e0, e1, e2, e3;
            {
                float x = (sc[qd*4+0] + SMOOTH_) * lw.x - SMOOTH_;
                e0 = mf.x * __expf(x - 50.f);
                x = (sc[qd*4+1] + SMOOTH_) * lw.y - SMOOTH_;
                e1 = mf.y * __expf(x - 50.f);
                x = (sc[qd*4+2] + SMOOTH_) * lw.z - SMOOTH_;
                e2 = mf.z * __expf(x - 50.f);
                x = (sc[qd*4+3] + SMOOTH_) * lw.w - SMOOTH_;
                e3 = mf.w * __expf(x - 50.f);
            }
            Z += (e0 + e1) + (e2 + e3);
            *(uint2*)&prow[qd * 8 + khalf * 4] =
                make_uint2(pk2(e0 * lw.x, e1 * lw.y), pk2(e2 * lw.z, e3 * lw.w));
        }

        // V^T A-frag: m=d on lanes (tl), k=s chunk (kg)
        bf16x8 vf = *(const bf16x8*)&Vt[tl * VSTR + i * 32 + kg * 8];

        // P B-frags per t-half: n=t (tl), k=s (kg)
        {
            const ushort* pr0 = &Pb[w][(0 * 16 + tl) * PSTR + kg * 8];
            U16 u;
            uint2 a0 = *(const uint2*)pr0;
            uint2 a1 = *(const uint2*)(pr0 + 4);
            u.u = make_uint4(a0.x, a0.y, a1.x, a1.y);
            o0 = __builtin_amdgcn_mfma_f32_16x16x32_bf16(vf, u.v, o0, 0, 0, 0);
            const ushort* pr1 = &Pb[w][(1 * 16 + tl) * PSTR + kg * 8];
            uint2 b0 = *(const uint2*)pr1;
            uint2 b1 = *(const uint2*)(pr1 + 4);
            u.u = make_uint4(b0.x, b0.y, b1.x, b1.y);
            o1 = __builtin_amdgcn_mfma_f32_16x16x32_bf16(vf, u.v, o1, 0, 0, 0);
        }
    }

    // ---- finalize Z: combine the two khalf s-subsets, publish per-wave ----
    Z += __shfl_xor(Z, 32);
    if (l < 32) Zbuf[w * 32 + tloc] = Z;
    __syncthreads();

    // ---- epilogue: O^T C-layout col=t (tl), row=d = kg*4 + r ----
#pragma unroll
    for (int th = 0; th < 2; ++th) {
        const float Zt  = Zbuf[w * 32 + th * 16 + tl];
        const float inv = (Zt > 0.f) ? 1.f / Zt : 0.f;
        const int   t   = thalf * 128 + w * 32 + th * 16 + tl;
        const f32x4 o   = th ? o1 : o0;
#pragma unroll
        for (int r = 0; r < 4; ++r) {
            const int d = kg * 4 + r;
            A[((size_t)t * B_ + b) * E_ + h * HD_ + d] = o[r] * inv;
        }
    }
}

// ---------------------------------------------------------------------------
extern "C" void kernel_launch(void* const* d_in, const int* in_sizes, int n_in,
                              void* d_out, int out_size, void* d_ws, size_t ws_size,
                              hipStream_t stream)
{
    const float* query = (const float*)d_in[0];
    const int*   oc    = (const int*)d_in[1];
    const int*   em    = (const int*)d_in[2];
    const int*   kpm   = (const int*)d_in[3];
    const float* law   = (const float*)d_in[4];
    const float* Wq    = (const float*)d_in[5];
    const float* bq    = (const float*)d_in[6];
    const float* Wk    = (const float*)d_in[7];
    const float* Wv    = (const float*)d_in[8];
    const float* bv    = (const float*)d_in[9];
    const float* Wo    = (const float*)d_in[10];
    const float* bo    = (const float*)d_in[11];
    float* out = (float*)d_out;

    float* ws = (float*)d_ws;
    float* Q = ws;                       // [B][H][T][16]
    float* K = Q + (size_t)1048576;      // [B][H][S][16]
    float* V = K + (size_t)3145728;      // [B][H][S][16]
    float* A = V + (size_t)3145728;      // [t][b][e]

    dim3 gq(E_ / 64, M_ / 64, 3);
    qkv_gemm<<<gq, 256, 0, stream>>>(query, Wq, bq, Wk, Wv, bv, Q, K, V);

    gather_kernel<<<B_ * EXP_, 256, 0, stream>>>(oc, K, V);

    attn_kernel<<<B_ * H_ * 2, 256, 0, stream>>>(Q, K, V, law, kpm, em, A);

    dim3 go(E_ / 64, M_ / 64, 1);
    out_gemm<<<go, 256, 0, stream>>>(A, Wo, bo, out);
}

// Round 7
// 130.104 us; speedup vs baseline: 3.4164x; 1.1514x over previous
//
#include <hip/hip_runtime.h>
#include <stdint.h>

#define T_ 256
#define B_ 8
#define E_ 512
#define H_ 32
#define HD_ 16
#define EXP_ 512
#define S_ 768          // T_ + EXP_
#define M_ 2048         // T_ * B_
#define SMOOTH_ 20.0f
#define PSTR 36         // P-tile LDS row stride (bf16)
#define VSTR 800        // V^T LDS row stride (bf16)

typedef __attribute__((ext_vector_type(8)))  short bf16x8;
typedef __attribute__((ext_vector_type(4)))  float f32x4;
typedef __attribute__((ext_vector_type(16))) float f32x16;

// RNE pack: two fp32 -> one dword of two bf16 (lo=a, hi=b)
__device__ __forceinline__ unsigned int pk2(float a, float b)
{
    unsigned int ua = __float_as_uint(a);
    ua = ua + 0x7FFFu + ((ua >> 16) & 1u);
    unsigned int ub = __float_as_uint(b);
    ub = ub + 0x7FFFu + ((ub >> 16) & 1u);
    return (ua >> 16) | (ub & 0xFFFF0000u);
}
__device__ __forceinline__ ushort bf1(float a)
{
    unsigned int u = __float_as_uint(a);
    u = u + 0x7FFFu + ((u >> 16) & 1u);
    return (ushort)(u >> 16);
}

union U16 { uint4 u; bf16x8 v; };

// ---------------------------------------------------------------------------
// conv: fp32 -> bf16 for X (4 segs) and Wq/Wk/Wv/Wo (1 seg each).
// 512 blocks x 256 thr; 16 elems/thread.
// ---------------------------------------------------------------------------
__global__ __launch_bounds__(256)
void conv_kernel(const float* __restrict__ X,
                 const float* __restrict__ Wq, const float* __restrict__ Wk,
                 const float* __restrict__ Wv, const float* __restrict__ Wo,
                 ushort* __restrict__ Xb, ushort* __restrict__ Wb)
{
    const int seg = blockIdx.x >> 6;
    const int blk = blockIdx.x & 63;
    const float* src;
    ushort* dst;
    if (seg < 4) { src = X + (size_t)seg * 262144; dst = Xb + (size_t)seg * 262144; }
    else {
        const float* ws_[4] = {Wq, Wk, Wv, Wo};
        src = ws_[seg - 4];
        dst = Wb + (size_t)(seg - 4) * 262144;
    }
    const int base = blk * 4096 + threadIdx.x * 16;
    float4 f0 = *(const float4*)&src[base + 0];
    float4 f1 = *(const float4*)&src[base + 4];
    float4 f2 = *(const float4*)&src[base + 8];
    float4 f3 = *(const float4*)&src[base + 12];
    *(uint4*)&dst[base + 0] = make_uint4(pk2(f0.x, f0.y), pk2(f0.z, f0.w),
                                         pk2(f1.x, f1.y), pk2(f1.z, f1.w));
    *(uint4*)&dst[base + 8] = make_uint4(pk2(f2.x, f2.y), pk2(f2.z, f2.w),
                                         pk2(f3.x, f3.y), pk2(f3.z, f3.w));
}

// ---------------------------------------------------------------------------
// bf16 MFMA GEMM body: C[m][n] = sum_k X[m][k]*W[n][k], both bf16 row-major.
// 64x64 tile, BK=64, staging = pure vector copy (no conversion).
// LDS stride 72 bf16 (144B): frag-read lanes land 2-way on banks (free).
// ---------------------------------------------------------------------------
__device__ __forceinline__ void mfma_gemm_body_bf(const ushort* __restrict__ X,
                                                  const ushort* __restrict__ W,
                                                  int m0, int n0,
                                                  f32x4 acc[2][2],
                                                  ushort* As, ushort* Bs)
{
    const int tid  = threadIdx.x;
    const int lrow = tid >> 2;
    const int kq   = tid & 3;
    const int l    = tid & 63;
    const int w    = tid >> 6;
    const int wm   = w & 1;
    const int wn   = w >> 1;
    const int lq   = l >> 4;
    const int ln   = l & 15;

    const ushort* Xr = &X[(size_t)(m0 + lrow) * E_ + kq * 16];
    const ushort* Wr = &W[(size_t)(n0 + lrow) * E_ + kq * 16];
    ushort* Aw = &As[lrow * 72 + kq * 16];
    ushort* Bw = &Bs[lrow * 72 + kq * 16];

    for (int k0 = 0; k0 < E_; k0 += 64) {
        uint4 a0 = *(const uint4*)&Xr[k0 + 0];
        uint4 a1 = *(const uint4*)&Xr[k0 + 8];
        uint4 b0 = *(const uint4*)&Wr[k0 + 0];
        uint4 b1 = *(const uint4*)&Wr[k0 + 8];
        __syncthreads();
        *(uint4*)&Aw[0] = a0;
        *(uint4*)&Aw[8] = a1;
        *(uint4*)&Bw[0] = b0;
        *(uint4*)&Bw[8] = b1;
        __syncthreads();
#pragma unroll
        for (int kb = 0; kb < 2; ++kb) {
            bf16x8 af0 = *(const bf16x8*)&As[(32 * wm + ln) * 72 + 32 * kb + lq * 8];
            bf16x8 af1 = *(const bf16x8*)&As[(32 * wm + 16 + ln) * 72 + 32 * kb + lq * 8];
            bf16x8 bf0 = *(const bf16x8*)&Bs[(32 * wn + ln) * 72 + 32 * kb + lq * 8];
            bf16x8 bf1 = *(const bf16x8*)&Bs[(32 * wn + 16 + ln) * 72 + 32 * kb + lq * 8];
            acc[0][0] = __builtin_amdgcn_mfma_f32_16x16x32_bf16(af0, bf0, acc[0][0], 0, 0, 0);
            acc[0][1] = __builtin_amdgcn_mfma_f32_16x16x32_bf16(af0, bf1, acc[0][1], 0, 0, 0);
            acc[1][0] = __builtin_amdgcn_mfma_f32_16x16x32_bf16(af1, bf0, acc[1][0], 0, 0, 0);
            acc[1][1] = __builtin_amdgcn_mfma_f32_16x16x32_bf16(af1, bf1, acc[1][1], 0, 0, 0);
        }
    }
}

// ---------------------------------------------------------------------------
// qkv GEMM: z=0 -> Qb[bh][t][16], z=1 -> Kb[bh][t][16], z=2 -> VTb[bh][d][t]
// (all bf16, T rows only; expansion happens in attn staging).
// ---------------------------------------------------------------------------
__global__ __launch_bounds__(256)
void qkv_gemm(const ushort* __restrict__ Xb, const ushort* __restrict__ Wb,
              const float* __restrict__ bq, const float* __restrict__ bv,
              ushort* __restrict__ Qb, ushort* __restrict__ Kb,
              ushort* __restrict__ VTb)
{
    __shared__ __align__(16) ushort As[64 * 72];
    __shared__ __align__(16) ushort Bs[64 * 72];
    const int z = blockIdx.z;
    const ushort* W    = Wb + (size_t)z * 262144;
    const float*  bias = (z == 0) ? bq : (z == 2 ? bv : nullptr);

    const int m0 = blockIdx.y * 64;
    const int n0 = blockIdx.x * 64;

    f32x4 acc[2][2];
#pragma unroll
    for (int i = 0; i < 2; ++i)
#pragma unroll
        for (int j = 0; j < 2; ++j)
            acc[i][j] = (f32x4){0.f, 0.f, 0.f, 0.f};

    mfma_gemm_body_bf(Xb, W, m0, n0, acc, As, Bs);

    const int l  = threadIdx.x & 63;
    const int w  = threadIdx.x >> 6;
    const int wm = w & 1;
    const int wn = w >> 1;
    const int lq = l >> 4;
    const int ln = l & 15;

#pragma unroll
    for (int j = 0; j < 2; ++j) {
        const int nb = n0 + 32 * wn + 16 * j;
        const int h  = nb >> 4;
        const int d  = ln;
        const float bv_ = bias ? bias[nb + ln] : 0.f;
#pragma unroll
        for (int i = 0; i < 2; ++i) {
#pragma unroll
            for (int r = 0; r < 4; ++r) {
                const int m = m0 + 32 * wm + 16 * i + lq * 4 + r;
                const int t = m >> 3;
                const int b = m & 7;
                const int bh = b * H_ + h;
                const ushort val = bf1(acc[i][j][r] + bv_);
                if (z == 0)      Qb[((size_t)bh * T_ + t) * HD_ + d] = val;
                else if (z == 1) Kb[((size_t)bh * T_ + t) * HD_ + d] = val;
                else             VTb[((size_t)bh * HD_ + d) * T_ + t] = val;
            }
        }
    }
}

// ---------------------------------------------------------------------------
// out GEMM: A = Ab (bf16, written by attn), B = Wob; fp32 output + bias.
// ---------------------------------------------------------------------------
__global__ __launch_bounds__(256)
void out_gemm(const ushort* __restrict__ Ab, const ushort* __restrict__ Wob,
              const float* __restrict__ bo, float* __restrict__ dst)
{
    __shared__ __align__(16) ushort As[64 * 72];
    __shared__ __align__(16) ushort Bs[64 * 72];
    const int m0 = blockIdx.y * 64;
    const int n0 = blockIdx.x * 64;

    f32x4 acc[2][2];
#pragma unroll
    for (int i = 0; i < 2; ++i)
#pragma unroll
        for (int j = 0; j < 2; ++j)
            acc[i][j] = (f32x4){0.f, 0.f, 0.f, 0.f};

    mfma_gemm_body_bf(Ab, Wob, m0, n0, acc, As, Bs);

    const int l  = threadIdx.x & 63;
    const int w  = threadIdx.x >> 6;
    const int wm = w & 1;
    const int wn = w >> 1;
    const int lq = l >> 4;
    const int ln = l & 15;

#pragma unroll
    for (int j = 0; j < 2; ++j) {
        const int nb = n0 + 32 * wn + 16 * j;
        const float bo_ = bo[nb + ln];
#pragma unroll
        for (int i = 0; i < 2; ++i) {
#pragma unroll
            for (int r = 0; r < 4; ++r) {
                const int m = m0 + 32 * wm + 16 * i + lq * 4 + r;
                dst[(size_t)m * E_ + nb + ln] = acc[i][j][r] + bo_;
            }
        }
    }
}

// ---------------------------------------------------------------------------
// Attention v5 (MFMA, bf16 in/out, fused K/V expansion):
// block = (b,h) x t-half, 256 thr / 4 waves, wave owns a 32-row t-tile.
// Stage: Ks[768][16] bf16 (rows 0..255 vector-copied from Kb, rows 256..767
// gathered via oc as 32B row copies); Vt[16][VSTR] bf16 (cols 0..255 vector
// copy from VTb, cols 256..767 scalar-gathered); msf[768] mask-as-float.
// Barrier-free s-loop: S^T = mfma_32x32x16(K,Q); fixed-ref softmax;
// P=e*law bf16 -> per-wave LDS tile; O^T += mfma_16x16x32(V^T, P).
// Epilogue: divide by Z, write Ab bf16 [m][e].
// ---------------------------------------------------------------------------
__global__ __launch_bounds__(256)
void attn_kernel(const ushort* __restrict__ Qb, const ushort* __restrict__ Kb,
                 const ushort* __restrict__ VTb, const float* __restrict__ LAW,
                 const int* __restrict__ kpm, const int* __restrict__ em,
                 const int* __restrict__ oc, ushort* __restrict__ Ab)
{
    __shared__ __align__(16) ushort Ks[S_ * HD_];       // 24576 B
    __shared__ __align__(16) ushort Vt[HD_ * VSTR];     // 25600 B
    __shared__ __align__(16) float  msf[S_];            // 3072 B
    __shared__ __align__(16) float  Zbuf[128];          // 512 B
    __shared__ __align__(16) ushort Pb[4][32 * PSTR];   // 9216 B

    const int tid    = threadIdx.x;
    const int blk    = blockIdx.x;
    const int bh     = blk >> 1;
    const int thalf  = blk & 1;
    const int b      = bh >> 5;
    const int h      = bh & 31;

    // ---- stage K rows 0..255 (vector copy) ----
    {
        const uint4* src = (const uint4*)&Kb[(size_t)bh * T_ * HD_];
        uint4* dst = (uint4*)Ks;
        dst[tid]       = src[tid];
        dst[tid + 256] = src[tid + 256];
    }
    // ---- stage V^T cols 0..255 (vector copy) ----
    {
#pragma unroll
        for (int it = 0; it < 2; ++it) {
            const int f = tid + it * 256;       // f < 512
            const int row = f >> 5, ch = f & 31;
            *(uint4*)&Vt[row * VSTR + ch * 8] =
                *(const uint4*)&VTb[((size_t)bh * HD_ + row) * T_ + ch * 8];
        }
    }
    // ---- expansion rows/cols 256..767 via oc ----
    {
#pragma unroll
        for (int it = 0; it < 2; ++it) {
            const int j = tid + it * 256;
            const int src = oc[b * EXP_ + j];
            const uint4* kr = (const uint4*)&Kb[((size_t)bh * T_ + src) * HD_];
            *(uint4*)&Ks[(T_ + j) * HD_ + 0] = kr[0];
            *(uint4*)&Ks[(T_ + j) * HD_ + 8] = kr[1];
#pragma unroll
            for (int d = 0; d < 16; ++d)
                Vt[d * VSTR + T_ + j] = VTb[((size_t)bh * HD_ + d) * T_ + src];
        }
    }
    // ---- masks ----
    {
#pragma unroll
        for (int it = 0; it < 3; ++it) {
            const int s = tid + it * 256;
            const int m = (s < T_) ? kpm[b * T_ + s] : em[b * EXP_ + (s - T_)];
            msf[s] = m ? 0.f : 1.f;
        }
    }

    // ---- Q fragment (direct bf16 load) ----
    const int w      = tid >> 6;
    const int l      = tid & 63;
    const int tloc   = l & 31;
    const int khalf  = l >> 5;
    const int tglob  = thalf * 128 + w * 32 + tloc;
    bf16x8 qf = *(const bf16x8*)&Qb[((size_t)bh * T_ + tglob) * HD_ + khalf * 8];

    __syncthreads();

    const f32x16 zero16 = {0.f,0.f,0.f,0.f,0.f,0.f,0.f,0.f,
                           0.f,0.f,0.f,0.f,0.f,0.f,0.f,0.f};
    f32x4 o0 = {0.f, 0.f, 0.f, 0.f};
    f32x4 o1 = {0.f, 0.f, 0.f, 0.f};
    float Z = 0.f;

    const float* lawp = &LAW[((size_t)b * T_ + tglob) * S_];
    ushort* prow = &Pb[w][tloc * PSTR];
    const int tl = l & 15;
    const int kg = l >> 4;

    for (int i = 0; i < S_ / 32; ++i) {
        bf16x8 kf = *(const bf16x8*)&Ks[(i * 32 + tloc) * HD_ + khalf * 8];
        f32x16 sc = __builtin_amdgcn_mfma_f32_32x32x16_bf16(kf, qf, zero16, 0, 0, 0);

#pragma unroll
        for (int qd = 0; qd < 4; ++qd) {
            const int sb = i * 32 + qd * 8 + khalf * 4;
            float4 mf = *(const float4*)&msf[sb];
            float4 lw = *(const float4*)&lawp[sb];
            float e0, e1, e2, e3;
            {
                float x = (sc[qd*4+0] + SMOOTH_) * lw.x - SMOOTH_;
                e0 = mf.x * __expf(x - 50.f);
                x = (sc[qd*4+1] + SMOOTH_) * lw.y - SMOOTH_;
                e1 = mf.y * __expf(x - 50.f);
                x = (sc[qd*4+2] + SMOOTH_) * lw.z - SMOOTH_;
                e2 = mf.z * __expf(x - 50.f);
                x = (sc[qd*4+3] + SMOOTH_) * lw.w - SMOOTH_;
                e3 = mf.w * __expf(x - 50.f);
            }
            Z += (e0 + e1) + (e2 + e3);
            *(uint2*)&prow[qd * 8 + khalf * 4] =
                make_uint2(pk2(e0 * lw.x, e1 * lw.y), pk2(e2 * lw.z, e3 * lw.w));
        }

        bf16x8 vf = *(const bf16x8*)&Vt[tl * VSTR + i * 32 + kg * 8];
        {
            const ushort* pr0 = &Pb[w][(0 * 16 + tl) * PSTR + kg * 8];
            U16 u;
            uint2 a0 = *(const uint2*)pr0;
            uint2 a1 = *(const uint2*)(pr0 + 4);
            u.u = make_uint4(a0.x, a0.y, a1.x, a1.y);
            o0 = __builtin_amdgcn_mfma_f32_16x16x32_bf16(vf, u.v, o0, 0, 0, 0);
            const ushort* pr1 = &Pb[w][(1 * 16 + tl) * PSTR + kg * 8];
            uint2 b0 = *(const uint2*)pr1;
            uint2 b1 = *(const uint2*)(pr1 + 4);
            u.u = make_uint4(b0.x, b0.y, b1.x, b1.y);
            o1 = __builtin_amdgcn_mfma_f32_16x16x32_bf16(vf, u.v, o1, 0, 0, 0);
        }
    }

    Z += __shfl_xor(Z, 32);
    if (l < 32) Zbuf[w * 32 + tloc] = Z;
    __syncthreads();

#pragma unroll
    for (int th = 0; th < 2; ++th) {
        const float Zt  = Zbuf[w * 32 + th * 16 + tl];
        const float inv = (Zt > 0.f) ? 1.f / Zt : 0.f;
        const int   t   = thalf * 128 + w * 32 + th * 16 + tl;
        const f32x4 o   = th ? o1 : o0;
#pragma unroll
        for (int r = 0; r < 4; ++r) {
            const int d = kg * 4 + r;
            Ab[((size_t)t * B_ + b) * E_ + h * HD_ + d] = bf1(o[r] * inv);
        }
    }
}

// ---------------------------------------------------------------------------
extern "C" void kernel_launch(void* const* d_in, const int* in_sizes, int n_in,
                              void* d_out, int out_size, void* d_ws, size_t ws_size,
                              hipStream_t stream)
{
    const float* query = (const float*)d_in[0];
    const int*   oc    = (const int*)d_in[1];
    const int*   em    = (const int*)d_in[2];
    const int*   kpm   = (const int*)d_in[3];
    const float* law   = (const float*)d_in[4];
    const float* Wq    = (const float*)d_in[5];
    const float* bq    = (const float*)d_in[6];
    const float* Wk    = (const float*)d_in[7];
    const float* Wv    = (const float*)d_in[8];
    const float* bv    = (const float*)d_in[9];
    const float* Wo    = (const float*)d_in[10];
    const float* bo    = (const float*)d_in[11];
    float* out = (float*)d_out;

    ushort* Xb  = (ushort*)d_ws;                 // [m][e]      1,048,576
    ushort* Wb  = Xb  + (size_t)1048576;         // 4x[n][k]    1,048,576
    ushort* Qb  = Wb  + (size_t)1048576;         // [bh][t][16] 1,048,576
    ushort* Kb  = Qb  + (size_t)1048576;         // [bh][t][16] 1,048,576
    ushort* VTb = Kb  + (size_t)1048576;         // [bh][d][t]  1,048,576
    ushort* Ab  = VTb + (size_t)1048576;         // [m][e]      1,048,576

    conv_kernel<<<512, 256, 0, stream>>>(query, Wq, Wk, Wv, Wo, Xb, Wb);

    dim3 gq(E_ / 64, M_ / 64, 3);
    qkv_gemm<<<gq, 256, 0, stream>>>(Xb, Wb, bq, bv, Qb, Kb, VTb);

    attn_kernel<<<B_ * H_ * 2, 256, 0, stream>>>(Qb, Kb, VTb, law, kpm, em, oc, Ab);

    dim3 go(E_ / 64, M_ / 64, 1);
    out_gemm<<<go, 256, 0, stream>>>(Ab, Wb + (size_t)3 * 262144, bo, out);
}